// Round 1
// baseline (237.120 us; speedup 1.0000x reference)
//
#include <hip/hip_runtime.h>
#include <math.h>

// YOLOX loss, fixed shapes: B=32, A = 80*80 + 40*40 + 20*20 = 8400, 85 channels.
constexpr int A_TOTAL = 8400;

__device__ __forceinline__ float bce(float x, float t) {
    // max(x,0) - x*t + log1p(exp(-|x|))
    return fmaxf(x, 0.0f) - x * t + log1pf(expf(-fabsf(x)));
}

__global__ __launch_bounds__(256) void yolox_main(
    const float* __restrict__ out0, const float* __restrict__ out1,
    const float* __restrict__ out2, const float* __restrict__ regt,
    const float* __restrict__ clst, const int* __restrict__ fgm,
    double* __restrict__ acc, int B)
{
    int g = blockIdx.x * blockDim.x + threadIdx.x;
    float local = 0.0f, fgl = 0.0f;
    int total = B * A_TOTAL;
    if (g < total) {
        int b = g / A_TOTAL;
        int r = g - b * A_TOTAL;
        const float* obase; int HW; float stride; int a, gx, gy;
        if (r < 6400) {
            obase = out0 + (size_t)b * 85 * 6400; HW = 6400; stride = 8.0f;
            a = r;        gx = a % 80; gy = a / 80;
        } else if (r < 8000) {
            obase = out1 + (size_t)b * 85 * 1600; HW = 1600; stride = 16.0f;
            a = r - 6400; gx = a % 40; gy = a / 40;
        } else {
            obase = out2 + (size_t)b * 85 * 400;  HW = 400;  stride = 32.0f;
            a = r - 8000; gx = a % 20; gy = a / 20;
        }
        // channels 0..4 (coalesced across lanes: consecutive anchors)
        float tx   = obase[a];
        float ty   = obase[(size_t)1 * HW + a];
        float tw   = obase[(size_t)2 * HW + a];
        float th   = obase[(size_t)3 * HW + a];
        float tobj = obase[(size_t)4 * HW + a];

        // decode
        float px = (tx + (float)gx) * stride;
        float py = (ty + (float)gy) * stride;
        float pw = expf(tw) * stride;
        float ph = expf(th) * stride;

        float4 t = reinterpret_cast<const float4*>(regt)[g];   // 16B aligned, coalesced
        float fgv = (float)fgm[g];

        // IoU loss
        float tlx = fmaxf(px - pw * 0.5f, t.x - t.z * 0.5f);
        float tly = fmaxf(py - ph * 0.5f, t.y - t.w * 0.5f);
        float brx = fminf(px + pw * 0.5f, t.x + t.z * 0.5f);
        float bry = fminf(py + ph * 0.5f, t.y + t.w * 0.5f);
        float area_p = pw * ph;
        float area_g = t.z * t.w;
        float en = ((tlx < brx) && (tly < bry)) ? 1.0f : 0.0f;
        float area_i = (brx - tlx) * (bry - tly) * en;
        float area_u = area_p + area_g - area_i;
        float iou = area_i / (area_u + 1e-16f);
        float l_iou = 1.0f - iou * iou;

        local = 5.0f * l_iou * fgv + bce(tobj, fgv);
        fgl = fgv;

        // cls loss only contributes when fg != 0 -> skip loads entirely otherwise
        if (fgv != 0.0f) {
            const float* cp = obase + (size_t)5 * HW + a;
            const float4* ct = reinterpret_cast<const float4*>(clst) + (size_t)g * 20;
            float cl = 0.0f;
            #pragma unroll 5
            for (int c4 = 0; c4 < 20; ++c4) {
                float4 tv = ct[c4];
                float x0 = cp[(size_t)(4 * c4 + 0) * HW];
                float x1 = cp[(size_t)(4 * c4 + 1) * HW];
                float x2 = cp[(size_t)(4 * c4 + 2) * HW];
                float x3 = cp[(size_t)(4 * c4 + 3) * HW];
                cl += bce(x0, tv.x) + bce(x1, tv.y) + bce(x2, tv.z) + bce(x3, tv.w);
            }
            local += cl * fgv;
        }
    }

    // wave (64) reduction
    for (int off = 32; off > 0; off >>= 1) {
        local += __shfl_down(local, off, 64);
        fgl   += __shfl_down(fgl,   off, 64);
    }
    __shared__ float s_loss[4], s_fg[4];
    int wid  = threadIdx.x >> 6;
    int lane = threadIdx.x & 63;
    if (lane == 0) { s_loss[wid] = local; s_fg[wid] = fgl; }
    __syncthreads();
    if (threadIdx.x == 0) {
        float bl = s_loss[0] + s_loss[1] + s_loss[2] + s_loss[3];
        float bf = s_fg[0]   + s_fg[1]   + s_fg[2]   + s_fg[3];
        atomicAdd(&acc[0], (double)bl);
        atomicAdd(&acc[1], (double)bf);
    }
}

__global__ void yolox_final(const double* __restrict__ acc, float* __restrict__ out) {
    out[0] = (float)(acc[0] / fmax(acc[1], 1.0));
}

extern "C" void kernel_launch(void* const* d_in, const int* in_sizes, int n_in,
                              void* d_out, int out_size, void* d_ws, size_t ws_size,
                              hipStream_t stream) {
    const float* out0 = (const float*)d_in[0];
    const float* out1 = (const float*)d_in[1];
    const float* out2 = (const float*)d_in[2];
    const float* regt = (const float*)d_in[3];
    const float* clst = (const float*)d_in[4];
    const int*   fgm  = (const int*)d_in[5];

    int B = in_sizes[0] / (85 * 6400);
    double* acc = (double*)d_ws;
    hipMemsetAsync(acc, 0, 2 * sizeof(double), stream);

    int total  = B * A_TOTAL;
    int blocks = (total + 255) / 256;
    hipLaunchKernelGGL(yolox_main, dim3(blocks), dim3(256), 0, stream,
                       out0, out1, out2, regt, clst, fgm, acc, B);
    hipLaunchKernelGGL(yolox_final, dim3(1), dim3(1), 0, stream, acc, (float*)d_out);
}

// Round 3
// 235.214 us; speedup vs baseline: 1.0081x; 1.0081x over previous
//
#include <hip/hip_runtime.h>
#include <math.h>

// YOLOX loss, fixed shapes: B=32, A = 80*80 + 40*40 + 20*20 = 8400, 85 channels.
constexpr int A_TOTAL = 8400;

__device__ __forceinline__ float bce(float x, float t) {
    // max(x,0) - x*t + softplus(-|x|); hw exp/log (v_exp_f32/v_log_f32)
    float ax = fabsf(x);
    float sp = __logf(1.0f + __expf(-ax));
    return fmaxf(x, 0.0f) - x * t + sp;
}

__device__ __forceinline__ void block_reduce_atomic(float v, float w, double* acc,
                                                    bool two) {
    for (int off = 32; off > 0; off >>= 1) {
        v += __shfl_down(v, off, 64);
        if (two) w += __shfl_down(w, off, 64);
    }
    __shared__ float s_v[4], s_w[4];
    int wid  = threadIdx.x >> 6;
    int lane = threadIdx.x & 63;
    if (lane == 0) { s_v[wid] = v; s_w[wid] = w; }
    __syncthreads();
    if (threadIdx.x == 0) {
        float bv = s_v[0] + s_v[1] + s_v[2] + s_v[3];
        atomicAdd(&acc[0], (double)bv);
        if (two) {
            float bw = s_w[0] + s_w[1] + s_w[2] + s_w[3];
            atomicAdd(&acc[1], (double)bw);
        }
    }
}

// Kernel 1: IoU + objectness + fg count. One thread per anchor. Fully coalesced.
__global__ __launch_bounds__(256) void yolox_iou_obj(
    const float* __restrict__ out0, const float* __restrict__ out1,
    const float* __restrict__ out2, const float* __restrict__ regt,
    const int* __restrict__ fgm, double* __restrict__ acc, int B)
{
    int g = blockIdx.x * blockDim.x + threadIdx.x;
    float local = 0.0f, fgl = 0.0f;
    int total = B * A_TOTAL;
    if (g < total) {
        int b = g / A_TOTAL;
        int r = g - b * A_TOTAL;
        const float* obase; int HW; float stride; int a, gx, gy;
        if (r < 6400) {
            obase = out0 + (size_t)b * 85 * 6400; HW = 6400; stride = 8.0f;
            a = r;        gx = a % 80; gy = a / 80;
        } else if (r < 8000) {
            obase = out1 + (size_t)b * 85 * 1600; HW = 1600; stride = 16.0f;
            a = r - 6400; gx = a % 40; gy = a / 40;
        } else {
            obase = out2 + (size_t)b * 85 * 400;  HW = 400;  stride = 32.0f;
            a = r - 8000; gx = a % 20; gy = a / 20;
        }
        float tx   = obase[a];
        float ty   = obase[(size_t)1 * HW + a];
        float tw   = obase[(size_t)2 * HW + a];
        float th   = obase[(size_t)3 * HW + a];
        float tobj = obase[(size_t)4 * HW + a];

        float px = (tx + (float)gx) * stride;
        float py = (ty + (float)gy) * stride;
        float pw = __expf(tw) * stride;
        float ph = __expf(th) * stride;

        float4 t = reinterpret_cast<const float4*>(regt)[g];
        float fgv = (float)fgm[g];

        float tlx = fmaxf(px - pw * 0.5f, t.x - t.z * 0.5f);
        float tly = fmaxf(py - ph * 0.5f, t.y - t.w * 0.5f);
        float brx = fminf(px + pw * 0.5f, t.x + t.z * 0.5f);
        float bry = fminf(py + ph * 0.5f, t.y + t.w * 0.5f);
        float area_p = pw * ph;
        float area_g = t.z * t.w;
        float en = ((tlx < brx) && (tly < bry)) ? 1.0f : 0.0f;
        float area_i = (brx - tlx) * (bry - tly) * en;
        float area_u = area_p + area_g - area_i;
        float iou = area_i / (area_u + 1e-16f);
        float l_iou = 1.0f - iou * iou;

        local = 5.0f * l_iou * fgv + bce(tobj, fgv);
        fgl = fgv;
    }
    block_reduce_atomic(local, fgl, acc, true);
}

// Kernel 2: classification BCE. 4 threads per anchor, each owns 20 classes.
//  - cls targets: per-thread contiguous 80B (5x float4); wave covers a
//    contiguous 5KB region -> coalesced.
//  - cls logits: channel-major; per load instr lanes hit 4 channels x 16
//    consecutive anchors = 4 fully-used 64B lines.
//  - fg==0 anchors skip all loads.
__global__ __launch_bounds__(256) void yolox_cls(
    const float* __restrict__ out0, const float* __restrict__ out1,
    const float* __restrict__ out2, const float* __restrict__ clst,
    const int* __restrict__ fgm, double* __restrict__ acc, int B)
{
    int t = blockIdx.x * blockDim.x + threadIdx.x;
    float local = 0.0f;
    int total4 = B * A_TOTAL * 4;
    if (t < total4) {
        int g = t >> 2;          // anchor
        int q = t & 3;           // class-quarter (20 classes)
        if (fgm[g] != 0) {
            int b = g / A_TOTAL;
            int r = g - b * A_TOTAL;
            const float* cp; int HW; int a;
            if (r < 6400) {
                cp = out0 + (size_t)b * 85 * 6400 + (size_t)5 * 6400; HW = 6400; a = r;
            } else if (r < 8000) {
                cp = out1 + (size_t)b * 85 * 1600 + (size_t)5 * 1600; HW = 1600; a = r - 6400;
            } else {
                cp = out2 + (size_t)b * 85 * 400  + (size_t)5 * 400;  HW = 400;  a = r - 8000;
            }
            cp += a + (size_t)(q * 20) * HW;
            const float4* ct = reinterpret_cast<const float4*>(clst + (size_t)g * 80 + q * 20);
            float cl = 0.0f;
            #pragma unroll
            for (int i = 0; i < 5; ++i) {
                float4 tv = ct[i];
                float x0 = cp[(size_t)(4 * i + 0) * HW];
                float x1 = cp[(size_t)(4 * i + 1) * HW];
                float x2 = cp[(size_t)(4 * i + 2) * HW];
                float x3 = cp[(size_t)(4 * i + 3) * HW];
                cl += bce(x0, tv.x) + bce(x1, tv.y) + bce(x2, tv.z) + bce(x3, tv.w);
            }
            local = cl;
        }
    }
    block_reduce_atomic(local, 0.0f, acc, false);
}

__global__ void yolox_final(const double* __restrict__ acc, float* __restrict__ out) {
    out[0] = (float)(acc[0] / fmax(acc[1], 1.0));
}

extern "C" void kernel_launch(void* const* d_in, const int* in_sizes, int n_in,
                              void* d_out, int out_size, void* d_ws, size_t ws_size,
                              hipStream_t stream) {
    const float* out0 = (const float*)d_in[0];
    const float* out1 = (const float*)d_in[1];
    const float* out2 = (const float*)d_in[2];
    const float* regt = (const float*)d_in[3];
    const float* clst = (const float*)d_in[4];
    const int*   fgm  = (const int*)d_in[5];

    int B = in_sizes[0] / (85 * 6400);
    double* acc = (double*)d_ws;
    hipMemsetAsync(acc, 0, 2 * sizeof(double), stream);

    int total  = B * A_TOTAL;
    int blocks1 = (total + 255) / 256;
    int blocks2 = (total * 4 + 255) / 256;
    hipLaunchKernelGGL(yolox_iou_obj, dim3(blocks1), dim3(256), 0, stream,
                       out0, out1, out2, regt, fgm, acc, B);
    hipLaunchKernelGGL(yolox_cls, dim3(blocks2), dim3(256), 0, stream,
                       out0, out1, out2, clst, fgm, acc, B);
    hipLaunchKernelGGL(yolox_final, dim3(1), dim3(1), 0, stream, acc, (float*)d_out);
}